// Round 12
// baseline (517.277 us; speedup 1.0000x reference)
//
#include <hip/hip_runtime.h>
#include <hip/hip_bf16.h>

#define NN 50000
#define NE 600000
#define NG 512

typedef __attribute__((ext_vector_type(8))) short bf16x8;
typedef __attribute__((ext_vector_type(4))) float f32x4;

__device__ __forceinline__ float bf_lo(unsigned u) {
    unsigned v = u << 16;
    return __builtin_bit_cast(float, v);
}
__device__ __forceinline__ float bf_hi(unsigned u) {
    unsigned v = u & 0xFFFF0000u;
    return __builtin_bit_cast(float, v);
}
__device__ __forceinline__ unsigned f2bf(float f) {  // RNE, returns in low 16 bits
    unsigned u = __builtin_bit_cast(unsigned, f);
    return (u + 0x7FFFu + ((u >> 16) & 1u)) >> 16;
}

__global__ __launch_bounds__(256) void k_zero(float* p, int n) {
    int i = blockIdx.x * 256 + threadIdx.x;
    if (i < n) p[i] = 0.0f;
}

// merged: in-degree + out-degree histograms (600k) + batch counts (50k)
__global__ __launch_bounds__(256) void k_histcnt(const int* __restrict__ src, const int* __restrict__ dst,
                                                 int* __restrict__ in_deg, int* __restrict__ out_deg,
                                                 const int* __restrict__ batch, float* __restrict__ counts) {
    int i = blockIdx.x * 256 + threadIdx.x;
    if (i < NE) {
        atomicAdd(&in_deg[dst[i]], 1);
        atomicAdd(&out_deg[src[i]], 1);
    }
    if (i < NN) atomicAdd(&counts[batch[i]], 1.0f);
}

// allocate dst-CSR rows (padded to PAD slots; zero cpk pad slots when PAD>1)
// + src-CSR rows (never padded) + dis.
__global__ __launch_bounds__(256) void k_alloc(const int* __restrict__ in_deg, const int* __restrict__ out_deg,
                                               int* __restrict__ gcur,
                                               int* __restrict__ rowstart, int* __restrict__ cursor,
                                               int* __restrict__ srowstart, int* __restrict__ scursor,
                                               float* __restrict__ dis, uint2* __restrict__ cpk, int pad) {
    int i = blockIdx.x * 256 + threadIdx.x;
    if (i >= NN) return;
    int d = in_deg[i];
    int dr = (d + pad - 1) & ~(pad - 1);
    int st = atomicAdd(gcur, dr);
    rowstart[i] = st;
    cursor[i] = st;
    dis[i] = 1.0f / sqrtf((float)(d + 1));
    for (int p = st + d; p < st + dr; ++p) cpk[p] = make_uint2(0u, 0u);
    int od = out_deg[i];
    int sst = atomicAdd(gcur + 1, od);
    srowstart[i] = sst;
    scursor[i] = sst;
}

// fill both CSRs. After this, cursor[i]/scursor[i] == true row ends.
// cpk[slot] = (src, w) for the gather fallback; scsr[sslot] = (dst_slot, w)
// for the push path.
__global__ __launch_bounds__(256) void k_fill(const int* __restrict__ src, const int* __restrict__ dst,
                                              const float* __restrict__ dis, int* __restrict__ cursor,
                                              int* __restrict__ scursor,
                                              uint2* __restrict__ cpk, uint2* __restrict__ scsr) {
    int e = blockIdx.x * 256 + threadIdx.x;
    if (e >= NE) return;
    int s = src[e], d = dst[e];
    float w = dis[s] * dis[d];
    int slot = atomicAdd(&cursor[d], 1);
    cpk[slot] = make_uint2((unsigned)s, __builtin_bit_cast(unsigned, w));
    int sslot = atomicAdd(&scursor[s], 1);
    scsr[sslot] = make_uint2((unsigned)slot, __builtin_bit_cast(unsigned, w));
}

// x (f32) -> bf16 packed (node-major)
__global__ __launch_bounds__(256) void k_cvt_x(const float4* __restrict__ in, uint2* __restrict__ out, int n4) {
    int i = blockIdx.x * 256 + threadIdx.x;
    if (i >= n4) return;
    float4 v = in[i];
    uint2 o;
    o.x = f2bf(v.x) | (f2bf(v.y) << 16);
    o.y = f2bf(v.z) | (f2bf(v.w) << 16);
    out[i] = o;
}

// W[k][c] f32 -> Wt[c][k] bf16, for 3 weight matrices
__global__ __launch_bounds__(256) void k_cvt_w(const float* __restrict__ W0, const float* __restrict__ W1,
                                               const float* __restrict__ W2, unsigned short* __restrict__ Wt) {
    int idx = blockIdx.x * 256 + threadIdx.x;
    if (idx >= 3 * 16384) return;
    int m = idx >> 14;
    int r = idx & 16383;
    int k = r >> 7, c = r & 127;
    const float* W = (m == 0) ? W0 : (m == 1) ? W1 : W2;
    Wt[m * 16384 + c * 128 + k] = (unsigned short)f2bf(W[k * 128 + c]);
}

// C[M,128](bf16) = A[M,128](bf16) @ W, W given transposed Wt[col][k] bf16.
__global__ __launch_bounds__(256) void k_gemm_mfma(const unsigned short* __restrict__ A,
                                                   const unsigned short* __restrict__ Wt,
                                                   unsigned short* __restrict__ C, int M) {
    int wave = threadIdx.x >> 6;
    int lane = threadIdx.x & 63;
    int rowbase = blockIdx.x * 64 + wave * 16;
    int lr = lane & 15;
    int kg = lane >> 4;

    int arow = rowbase + lr;
    if (arow >= M) arow = M - 1;
    bf16x8 a[4];
#pragma unroll
    for (int kt = 0; kt < 4; ++kt)
        a[kt] = *(const bf16x8*)&A[arow * 128 + kt * 32 + kg * 8];

    f32x4 acc[8];
#pragma unroll
    for (int nt = 0; nt < 8; ++nt) acc[nt] = (f32x4){0.f, 0.f, 0.f, 0.f};

#pragma unroll
    for (int nt = 0; nt < 8; ++nt) {
        const unsigned short* wp = &Wt[(nt * 16 + lr) * 128 + kg * 8];
#pragma unroll
        for (int kt = 0; kt < 4; ++kt) {
            bf16x8 b = *(const bf16x8*)&wp[kt * 32];
            acc[nt] = __builtin_amdgcn_mfma_f32_16x16x32_bf16(a[kt], b, acc[nt], 0, 0, 0);
        }
    }

    int crow0 = rowbase + (lane >> 4) * 4;
#pragma unroll
    for (int nt = 0; nt < 8; ++nt) {
#pragma unroll
        for (int r = 0; r < 4; ++r) {
            int gr = crow0 + r;
            if (gr < M) C[gr * 128 + nt * 16 + lr] = (unsigned short)f2bf(acc[nt][r]);
        }
    }
}

// PUSH phase: 32 lanes/src-node. Read h[src] once (coalesced), stream the
// src-CSR row (broadcast 8B meta loads), and for each out-edge fire one
// 256 B full-line bf16 message store to its dst-slot. No load-dependency
// chain -> purely throughput-bound random writes.
__global__ __launch_bounds__(256) void k_push(const uint2* __restrict__ h,
                                              const int* __restrict__ srowstart,
                                              const int* __restrict__ srowend,
                                              const uint2* __restrict__ scsr,
                                              uint2* __restrict__ msg) {
    int t = blockIdx.x * 256 + threadIdx.x;
    int node = t >> 5;
    if (node >= NN) return;
    int f = t & 31;
    uint2 hv = h[node * 32 + f];
    float h0 = bf_lo(hv.x), h1 = bf_hi(hv.x), h2 = bf_lo(hv.y), h3 = bf_hi(hv.y);
    int s = srowstart[node];
    int e = srowend[node];
    for (; s < e; ++s) {
        uint2 q = scsr[s];
        float w = __builtin_bit_cast(float, q.y);
        uint2 o;
        o.x = f2bf(h0 * w) | (f2bf(h1 * w) << 16);
        o.y = f2bf(h2 * w) | (f2bf(h3 * w) << 16);
        msg[(int)q.x * 32 + f] = o;
    }
}

// SUM phase: 32 lanes/dst-node. Messages for a node are CONTIGUOUS slots ->
// sequential coalesced reads at streaming BW. 4-wide unrolled, f32 accum.
// Fuses self-loop + bias + relu (+ mean-pool accumulate for last layer).
template <int POOL>
__global__ __launch_bounds__(256) void k_sum(const uint2* __restrict__ msg,
                                             const uint2* __restrict__ h,
                                             const int* __restrict__ rowstart,
                                             const int* __restrict__ rowend,
                                             const float* __restrict__ dis,
                                             const float* __restrict__ bias,
                                             uint2* __restrict__ outbuf,
                                             const int* __restrict__ batch,
                                             float* __restrict__ sums) {
    int t = blockIdx.x * 256 + threadIdx.x;
    int node = t >> 5;
    if (node >= NN) return;
    int f = t & 31;

    float d = dis[node];
    float ws = d * d;
    uint2 hv = h[node * 32 + f];
    float a0 = bf_lo(hv.x) * ws;
    float a1 = bf_hi(hv.x) * ws;
    float a2 = bf_lo(hv.y) * ws;
    float a3 = bf_hi(hv.y) * ws;

    int s = rowstart[node];
    int e = rowend[node];
    for (; s + 3 < e; s += 4) {
        uint2 m0 = msg[(s + 0) * 32 + f];
        uint2 m1 = msg[(s + 1) * 32 + f];
        uint2 m2 = msg[(s + 2) * 32 + f];
        uint2 m3 = msg[(s + 3) * 32 + f];
        a0 += bf_lo(m0.x) + bf_lo(m1.x) + bf_lo(m2.x) + bf_lo(m3.x);
        a1 += bf_hi(m0.x) + bf_hi(m1.x) + bf_hi(m2.x) + bf_hi(m3.x);
        a2 += bf_lo(m0.y) + bf_lo(m1.y) + bf_lo(m2.y) + bf_lo(m3.y);
        a3 += bf_hi(m0.y) + bf_hi(m1.y) + bf_hi(m2.y) + bf_hi(m3.y);
    }
    for (; s < e; ++s) {
        uint2 m = msg[s * 32 + f];
        a0 += bf_lo(m.x);
        a1 += bf_hi(m.x);
        a2 += bf_lo(m.y);
        a3 += bf_hi(m.y);
    }

    float4 b = ((const float4*)bias)[f];
    a0 = fmaxf(a0 + b.x, 0.f);
    a1 = fmaxf(a1 + b.y, 0.f);
    a2 = fmaxf(a2 + b.z, 0.f);
    a3 = fmaxf(a3 + b.w, 0.f);

    if (POOL == 0) {
        uint2 o;
        o.x = f2bf(a0) | (f2bf(a1) << 16);
        o.y = f2bf(a2) | (f2bf(a3) << 16);
        outbuf[node * 32 + f] = o;
    } else {
        int g = batch[node];
        float* o = sums + g * 128 + f * 4;
        atomicAdd(o + 0, a0);
        atomicAdd(o + 1, a1);
        atomicAdd(o + 2, a2);
        atomicAdd(o + 3, a3);
    }
}

// FALLBACK (R11): gather aggregation, 32 thr/node, 8-deep chains + meta
// prefetch. Used when ws_size can't hold the msg buffer.
template <int POOL>
__global__ __launch_bounds__(256) void k_gather(const uint2* __restrict__ h,
                                                const int* __restrict__ rowstart,
                                                const int* __restrict__ rowend,
                                                const uint2* __restrict__ cpk,
                                                const float* __restrict__ dis,
                                                const float* __restrict__ bias,
                                                uint2* __restrict__ outbuf,
                                                const int* __restrict__ batch,
                                                float* __restrict__ sums) {
    int t = blockIdx.x * 256 + threadIdx.x;
    int node = t >> 5;
    if (node >= NN) return;
    int f = t & 31;

    int s0 = rowstart[node];
    int e0 = rowend[node];

    float acc[8][4];
#pragma unroll
    for (int j = 0; j < 8; ++j)
#pragma unroll
        for (int k = 0; k < 4; ++k) acc[j][k] = 0.f;

    const uint4* mp = (const uint4*)cpk;
    uint4 m0, m1, m2, m3;
    {
        int b = s0 >> 1;
        m0 = mp[b]; m1 = mp[b + 1]; m2 = mp[b + 2]; m3 = mp[b + 3];
    }

    for (int s = s0; s < e0; s += 8) {
        uint4 c0 = m0, c1 = m1, c2 = m2, c3 = m3;
        int sn = s + 8;
        int b = (sn < e0 ? sn : s0) >> 1;
        m0 = mp[b]; m1 = mp[b + 1]; m2 = mp[b + 2]; m3 = mp[b + 3];

        uint2 v0 = h[(int)c0.x * 32 + f];
        uint2 v1 = h[(int)c0.z * 32 + f];
        uint2 v2 = h[(int)c1.x * 32 + f];
        uint2 v3 = h[(int)c1.z * 32 + f];
        uint2 v4 = h[(int)c2.x * 32 + f];
        uint2 v5 = h[(int)c2.z * 32 + f];
        uint2 v6 = h[(int)c3.x * 32 + f];
        uint2 v7 = h[(int)c3.z * 32 + f];
        float w0 = __builtin_bit_cast(float, c0.y);
        float w1 = __builtin_bit_cast(float, c0.w);
        float w2 = __builtin_bit_cast(float, c1.y);
        float w3 = __builtin_bit_cast(float, c1.w);
        float w4 = __builtin_bit_cast(float, c2.y);
        float w5 = __builtin_bit_cast(float, c2.w);
        float w6 = __builtin_bit_cast(float, c3.y);
        float w7 = __builtin_bit_cast(float, c3.w);

        acc[0][0] = fmaf(bf_lo(v0.x), w0, acc[0][0]);
        acc[0][1] = fmaf(bf_hi(v0.x), w0, acc[0][1]);
        acc[0][2] = fmaf(bf_lo(v0.y), w0, acc[0][2]);
        acc[0][3] = fmaf(bf_hi(v0.y), w0, acc[0][3]);
        acc[1][0] = fmaf(bf_lo(v1.x), w1, acc[1][0]);
        acc[1][1] = fmaf(bf_hi(v1.x), w1, acc[1][1]);
        acc[1][2] = fmaf(bf_lo(v1.y), w1, acc[1][2]);
        acc[1][3] = fmaf(bf_hi(v1.y), w1, acc[1][3]);
        acc[2][0] = fmaf(bf_lo(v2.x), w2, acc[2][0]);
        acc[2][1] = fmaf(bf_hi(v2.x), w2, acc[2][1]);
        acc[2][2] = fmaf(bf_lo(v2.y), w2, acc[2][2]);
        acc[2][3] = fmaf(bf_hi(v2.y), w2, acc[2][3]);
        acc[3][0] = fmaf(bf_lo(v3.x), w3, acc[3][0]);
        acc[3][1] = fmaf(bf_hi(v3.x), w3, acc[3][1]);
        acc[3][2] = fmaf(bf_lo(v3.y), w3, acc[3][2]);
        acc[3][3] = fmaf(bf_hi(v3.y), w3, acc[3][3]);
        acc[4][0] = fmaf(bf_lo(v4.x), w4, acc[4][0]);
        acc[4][1] = fmaf(bf_hi(v4.x), w4, acc[4][1]);
        acc[4][2] = fmaf(bf_lo(v4.y), w4, acc[4][2]);
        acc[4][3] = fmaf(bf_hi(v4.y), w4, acc[4][3]);
        acc[5][0] = fmaf(bf_lo(v5.x), w5, acc[5][0]);
        acc[5][1] = fmaf(bf_hi(v5.x), w5, acc[5][1]);
        acc[5][2] = fmaf(bf_lo(v5.y), w5, acc[5][2]);
        acc[5][3] = fmaf(bf_hi(v5.y), w5, acc[5][3]);
        acc[6][0] = fmaf(bf_lo(v6.x), w6, acc[6][0]);
        acc[6][1] = fmaf(bf_hi(v6.x), w6, acc[6][1]);
        acc[6][2] = fmaf(bf_lo(v6.y), w6, acc[6][2]);
        acc[6][3] = fmaf(bf_hi(v6.y), w6, acc[6][3]);
        acc[7][0] = fmaf(bf_lo(v7.x), w7, acc[7][0]);
        acc[7][1] = fmaf(bf_hi(v7.x), w7, acc[7][1]);
        acc[7][2] = fmaf(bf_lo(v7.y), w7, acc[7][2]);
        acc[7][3] = fmaf(bf_hi(v7.y), w7, acc[7][3]);
    }

    float d = dis[node];
    float ws = d * d;
    uint2 hv = h[node * 32 + f];
    acc[0][0] = fmaf(bf_lo(hv.x), ws, acc[0][0]);
    acc[0][1] = fmaf(bf_hi(hv.x), ws, acc[0][1]);
    acc[0][2] = fmaf(bf_lo(hv.y), ws, acc[0][2]);
    acc[0][3] = fmaf(bf_hi(hv.y), ws, acc[0][3]);

    float a0 = ((acc[0][0] + acc[1][0]) + (acc[2][0] + acc[3][0])) +
               ((acc[4][0] + acc[5][0]) + (acc[6][0] + acc[7][0]));
    float a1 = ((acc[0][1] + acc[1][1]) + (acc[2][1] + acc[3][1])) +
               ((acc[4][1] + acc[5][1]) + (acc[6][1] + acc[7][1]));
    float a2 = ((acc[0][2] + acc[1][2]) + (acc[2][2] + acc[3][2])) +
               ((acc[4][2] + acc[5][2]) + (acc[6][2] + acc[7][2]));
    float a3 = ((acc[0][3] + acc[1][3]) + (acc[2][3] + acc[3][3])) +
               ((acc[4][3] + acc[5][3]) + (acc[6][3] + acc[7][3]));

    float4 b = ((const float4*)bias)[f];
    a0 = fmaxf(a0 + b.x, 0.f);
    a1 = fmaxf(a1 + b.y, 0.f);
    a2 = fmaxf(a2 + b.z, 0.f);
    a3 = fmaxf(a3 + b.w, 0.f);

    if (POOL == 0) {
        uint2 o;
        o.x = f2bf(a0) | (f2bf(a1) << 16);
        o.y = f2bf(a2) | (f2bf(a3) << 16);
        outbuf[node * 32 + f] = o;
    } else {
        int g = batch[node];
        float* o = sums + g * 128 + f * 4;
        atomicAdd(o + 0, a0);
        atomicAdd(o + 1, a1);
        atomicAdd(o + 2, a2);
        atomicAdd(o + 3, a3);
    }
}

// 512 blocks x 64 threads: pooled = sums/count; logits = pooled@Wf + bf; log_softmax
__global__ __launch_bounds__(64) void k_head(const float* __restrict__ sums,
                                             const float* __restrict__ counts,
                                             const float* __restrict__ Wf,
                                             const float* __restrict__ bf,
                                             float* __restrict__ out) {
    int g = blockIdx.x;
    int l = threadIdx.x;
    float inv = 1.0f / fmaxf(counts[g], 1.0f);
    float p0 = sums[g * 128 + l] * inv;
    float p1 = sums[g * 128 + 64 + l] * inv;
    float logit[10];
#pragma unroll
    for (int o = 0; o < 10; ++o) {
        float part = p0 * Wf[l * 10 + o] + p1 * Wf[(l + 64) * 10 + o];
#pragma unroll
        for (int s = 32; s > 0; s >>= 1) part += __shfl_xor(part, s);
        logit[o] = part + bf[o];
    }
    if (l == 0) {
        float m = logit[0];
#pragma unroll
        for (int o = 1; o < 10; ++o) m = fmaxf(m, logit[o]);
        float sum = 0.f;
#pragma unroll
        for (int o = 0; o < 10; ++o) sum += expf(logit[o] - m);
        float lse = m + logf(sum);
#pragma unroll
        for (int o = 0; o < 10; ++o) out[g * 10 + o] = logit[o] - lse;
    }
}

extern "C" void kernel_launch(void* const* d_in, const int* in_sizes, int n_in,
                              void* d_out, int out_size, void* d_ws, size_t ws_size,
                              hipStream_t stream) {
    const float* x     = (const float*)d_in[0];
    const int*   ei    = (const int*)d_in[1];
    const int*   batch = (const int*)d_in[2];
    const float* W0 = (const float*)d_in[3];
    const float* b0 = (const float*)d_in[4];
    const float* W1 = (const float*)d_in[5];
    const float* b1 = (const float*)d_in[6];
    const float* W2 = (const float*)d_in[7];
    const float* b2 = (const float*)d_in[8];
    const float* Wf = (const float*)d_in[9];
    const float* bf = (const float*)d_in[10];
    float* out = (float*)d_out;

    float* ws = (float*)d_ws;
    // float-offset layout
    float* sums     = ws;                      // 65536
    float* counts   = ws + 65536;              // 512    -> 66048
    int*   in_deg   = (int*)(ws + 66048);      // 50048  -> 116096
    int*   out_deg  = (int*)(ws + 116096);     // 50048  -> 166144
    int*   gcur     = (int*)(ws + 166144);     // 64     -> 166208
    float* dis      = ws + 166208;             // 50048  -> 216256
    int*   rowstart = (int*)(ws + 216256);     // 50048  -> 266304
    int*   cursor   = (int*)(ws + 266304);     // 50048  -> 316352
    int*   srowstart= (int*)(ws + 316352);     // 50048  -> 366400
    int*   scursor  = (int*)(ws + 366400);     // 50048  -> 416448
    uint2* cpk      = (uint2*)(ws + 416448);   // 950080 uint2 = 1900160 -> 2316608
    uint2* scsr     = (uint2*)(ws + 2316608);  // 600064 uint2 = 1200128 -> 3516736
    unsigned short* Wt = (unsigned short*)(ws + 3516736);  // 49152 us = 24576 -> 3541312
    unsigned short* bx = (unsigned short*)(ws + 3541312);  // -> 6741312
    unsigned short* hA = (unsigned short*)(ws + 6741312);  // -> 9941312
    unsigned short* hB = (unsigned short*)(ws + 9941312);  // -> 13141312
    uint2* msg      = (uint2*)(ws + 13141312); // 600064*32 uint2 = 38404096 f -> 51545408

    const bool use_msg = ws_size >= (size_t)51545408 * 4;
    const int pad = use_msg ? 1 : 8;

    const int* src = ei;
    const int* dst = ei + NE;

    // --- CSR build + norms + pool counts + conversions ---
    k_zero<<<(166208 + 255) / 256, 256, 0, stream>>>(ws, 166208);
    k_histcnt<<<2344, 256, 0, stream>>>(src, dst, in_deg, out_deg, batch, counts);
    k_alloc<<<196, 256, 0, stream>>>(in_deg, out_deg, gcur, rowstart, cursor,
                                     srowstart, scursor, dis, cpk, pad);
    k_fill<<<2344, 256, 0, stream>>>(src, dst, dis, cursor, scursor, cpk, scsr);
    k_cvt_x<<<6250, 256, 0, stream>>>((const float4*)x, (uint2*)bx, NN * 32);
    k_cvt_w<<<192, 256, 0, stream>>>(W0, W1, W2, Wt);

    const int GEMM_GRID = (NN + 63) / 64;

    if (use_msg) {
        // layer 0
        k_gemm_mfma<<<GEMM_GRID, 256, 0, stream>>>(bx, Wt, hB, NN);
        k_push<<<6250, 256, 0, stream>>>((const uint2*)hB, srowstart, scursor, scsr, msg);
        k_sum<0><<<6250, 256, 0, stream>>>(msg, (const uint2*)hB, rowstart, cursor,
                                           dis, b0, (uint2*)hA, batch, sums);
        // layer 1
        k_gemm_mfma<<<GEMM_GRID, 256, 0, stream>>>(hA, Wt + 16384, hB, NN);
        k_push<<<6250, 256, 0, stream>>>((const uint2*)hB, srowstart, scursor, scsr, msg);
        k_sum<0><<<6250, 256, 0, stream>>>(msg, (const uint2*)hB, rowstart, cursor,
                                           dis, b1, (uint2*)hA, batch, sums);
        // layer 2
        k_gemm_mfma<<<GEMM_GRID, 256, 0, stream>>>(hA, Wt + 32768, hB, NN);
        k_push<<<6250, 256, 0, stream>>>((const uint2*)hB, srowstart, scursor, scsr, msg);
        k_sum<1><<<6250, 256, 0, stream>>>(msg, (const uint2*)hB, rowstart, cursor,
                                           dis, b2, nullptr, batch, sums);
    } else {
        // fallback: R11 gather path
        k_gemm_mfma<<<GEMM_GRID, 256, 0, stream>>>(bx, Wt, hB, NN);
        k_gather<0><<<6250, 256, 0, stream>>>((const uint2*)hB, rowstart, cursor, cpk,
                                              dis, b0, (uint2*)hA, batch, sums);
        k_gemm_mfma<<<GEMM_GRID, 256, 0, stream>>>(hA, Wt + 16384, hB, NN);
        k_gather<0><<<6250, 256, 0, stream>>>((const uint2*)hB, rowstart, cursor, cpk,
                                              dis, b1, (uint2*)hA, batch, sums);
        k_gemm_mfma<<<GEMM_GRID, 256, 0, stream>>>(hA, Wt + 32768, hB, NN);
        k_gather<1><<<6250, 256, 0, stream>>>((const uint2*)hB, rowstart, cursor, cpk,
                                              dis, b2, nullptr, batch, sums);
    }

    k_head<<<512, 64, 0, stream>>>(sums, counts, Wf, bf, out);
}

// Round 13
// 363.291 us; speedup vs baseline: 1.4239x; 1.4239x over previous
//
#include <hip/hip_runtime.h>
#include <hip/hip_bf16.h>

#define NN 50000
#define NE 600000
#define NG 512

typedef __attribute__((ext_vector_type(8))) short bf16x8;
typedef __attribute__((ext_vector_type(4))) float f32x4;

__device__ __forceinline__ float bf_lo(unsigned u) {
    unsigned v = u << 16;
    return __builtin_bit_cast(float, v);
}
__device__ __forceinline__ float bf_hi(unsigned u) {
    unsigned v = u & 0xFFFF0000u;
    return __builtin_bit_cast(float, v);
}
__device__ __forceinline__ unsigned f2bf(float f) {  // RNE, returns in low 16 bits
    unsigned u = __builtin_bit_cast(unsigned, f);
    return (u + 0x7FFFu + ((u >> 16) & 1u)) >> 16;
}

__global__ __launch_bounds__(256) void k_zero(float* p, int n) {
    int i = blockIdx.x * 256 + threadIdx.x;
    if (i < n) p[i] = 0.0f;
}

__global__ __launch_bounds__(256) void k_hist(const int* __restrict__ dst, int* __restrict__ deg) {
    int e = blockIdx.x * 256 + threadIdx.x;
    if (e < NE) atomicAdd(&deg[dst[e]], 1);
}

__global__ __launch_bounds__(256) void k_counts(const int* __restrict__ batch, float* __restrict__ counts) {
    int i = blockIdx.x * 256 + threadIdx.x;
    if (i < NN) atomicAdd(&counts[batch[i]], 1.0f);
}

// allocate CSR row (padded to multiple of 4 slots); zero the pad slots
// (src=0, w=0 -> contributes nothing, row 0 is cache-hot).
__global__ __launch_bounds__(256) void k_alloc(const int* __restrict__ deg, int* __restrict__ gcur,
                                               int* __restrict__ rowstart, int* __restrict__ cursor,
                                               float* __restrict__ dis, uint2* __restrict__ cpk) {
    int i = blockIdx.x * 256 + threadIdx.x;
    if (i >= NN) return;
    int d = deg[i];
    int dr = (d + 3) & ~3;
    int st = atomicAdd(gcur, dr);
    rowstart[i] = st;
    cursor[i] = st;
    dis[i] = 1.0f / sqrtf((float)(d + 1));
    for (int p = st + d; p < st + dr; ++p) cpk[p] = make_uint2(0u, 0u);
}

// fill CSR slots: packed (src, weight). After this, cursor[i] == true row end.
__global__ __launch_bounds__(256) void k_fill(const int* __restrict__ src, const int* __restrict__ dst,
                                              const float* __restrict__ dis, int* __restrict__ cursor,
                                              uint2* __restrict__ cpk) {
    int e = blockIdx.x * 256 + threadIdx.x;
    if (e >= NE) return;
    int s = src[e], d = dst[e];
    int slot = atomicAdd(&cursor[d], 1);
    cpk[slot] = make_uint2((unsigned)s, __builtin_bit_cast(unsigned, dis[s] * dis[d]));
}

// x (f32) -> bf16 packed
__global__ __launch_bounds__(256) void k_cvt_x(const float4* __restrict__ in, uint2* __restrict__ out, int n4) {
    int i = blockIdx.x * 256 + threadIdx.x;
    if (i >= n4) return;
    float4 v = in[i];
    uint2 o;
    o.x = f2bf(v.x) | (f2bf(v.y) << 16);
    o.y = f2bf(v.z) | (f2bf(v.w) << 16);
    out[i] = o;
}

// W[k][c] f32 -> Wt[c][k] bf16, for 3 weight matrices
__global__ __launch_bounds__(256) void k_cvt_w(const float* __restrict__ W0, const float* __restrict__ W1,
                                               const float* __restrict__ W2, unsigned short* __restrict__ Wt) {
    int idx = blockIdx.x * 256 + threadIdx.x;
    if (idx >= 3 * 16384) return;
    int m = idx >> 14;
    int r = idx & 16383;
    int k = r >> 7, c = r & 127;
    const float* W = (m == 0) ? W0 : (m == 1) ? W1 : W2;
    Wt[m * 16384 + c * 128 + k] = (unsigned short)f2bf(W[k * 128 + c]);
}

// C[M,128](bf16) = A[M,128](bf16) @ W[128,128], W given transposed Wt[col][k] bf16.
// 256 thr = 4 waves; each wave: 16 rows x 128 cols via mfma_f32_16x16x32_bf16.
__global__ __launch_bounds__(256) void k_gemm_mfma(const unsigned short* __restrict__ A,
                                                   const unsigned short* __restrict__ Wt,
                                                   unsigned short* __restrict__ C, int M) {
    int wave = threadIdx.x >> 6;
    int lane = threadIdx.x & 63;
    int rowbase = blockIdx.x * 64 + wave * 16;
    int lr = lane & 15;   // A row within tile / B col within tile
    int kg = lane >> 4;   // k-group 0..3 (8 elems each)

    int arow = rowbase + lr;
    if (arow >= M) arow = M - 1;
    bf16x8 a[4];
#pragma unroll
    for (int kt = 0; kt < 4; ++kt)
        a[kt] = *(const bf16x8*)&A[arow * 128 + kt * 32 + kg * 8];

    f32x4 acc[8];
#pragma unroll
    for (int nt = 0; nt < 8; ++nt) acc[nt] = (f32x4){0.f, 0.f, 0.f, 0.f};

#pragma unroll
    for (int nt = 0; nt < 8; ++nt) {
        const unsigned short* wp = &Wt[(nt * 16 + lr) * 128 + kg * 8];
#pragma unroll
        for (int kt = 0; kt < 4; ++kt) {
            bf16x8 b = *(const bf16x8*)&wp[kt * 32];
            acc[nt] = __builtin_amdgcn_mfma_f32_16x16x32_bf16(a[kt], b, acc[nt], 0, 0, 0);
        }
    }

    int crow0 = rowbase + (lane >> 4) * 4;  // C/D: col = lane&15, row = (lane>>4)*4 + r
#pragma unroll
    for (int nt = 0; nt < 8; ++nt) {
#pragma unroll
        for (int r = 0; r < 4; ++r) {
            int gr = crow0 + r;
            if (gr < M) C[gr * 128 + nt * 16 + lr] = (unsigned short)f2bf(acc[nt][r]);
        }
    }
}

// Gather aggregation over bf16 features, 32 threads/node (uint2 = 4 bf16 each),
// 2 nodes per wave. 4-deep manual unroll with 4 independent accumulator
// chains: CSR rows are padded to multiples of 4 with w=0 slots, so each
// iteration issues 2 aligned uint4 metadata loads + 4 independent h-row
// loads before any wait. f32 accumulate; fuses self-loop + bias + relu.
template <int POOL>
__global__ __launch_bounds__(256) void k_gather(const uint2* __restrict__ h,
                                                const int* __restrict__ rowstart,
                                                const int* __restrict__ rowend,
                                                const uint2* __restrict__ cpk,
                                                const float* __restrict__ dis,
                                                const float* __restrict__ bias,
                                                uint2* __restrict__ outbuf,
                                                const int* __restrict__ batch,
                                                float* __restrict__ sums) {
    int t = blockIdx.x * 256 + threadIdx.x;
    int node = t >> 5;
    if (node >= NN) return;
    int f = t & 31;  // cols f*4 .. f*4+3

    int s0 = rowstart[node];
    int e0 = rowend[node];  // true end; padded region extends to next mult of 4

    float A0 = 0.f, A1 = 0.f, A2 = 0.f, A3 = 0.f;
    float B0 = 0.f, B1 = 0.f, B2 = 0.f, B3 = 0.f;
    float C0 = 0.f, C1 = 0.f, C2 = 0.f, C3 = 0.f;
    float D0 = 0.f, D1 = 0.f, D2 = 0.f, D3 = 0.f;

    for (int s = s0; s < e0; s += 4) {
        uint4 q01 = *(const uint4*)&cpk[s];       // (src0,w0,src1,w1)
        uint4 q23 = *(const uint4*)&cpk[s + 2];   // (src2,w2,src3,w3)
        uint2 v0 = h[(int)q01.x * 32 + f];
        uint2 v1 = h[(int)q01.z * 32 + f];
        uint2 v2 = h[(int)q23.x * 32 + f];
        uint2 v3 = h[(int)q23.z * 32 + f];
        float w0 = __builtin_bit_cast(float, q01.y);
        float w1 = __builtin_bit_cast(float, q01.w);
        float w2 = __builtin_bit_cast(float, q23.y);
        float w3 = __builtin_bit_cast(float, q23.w);
        A0 = fmaf(bf_lo(v0.x), w0, A0);
        A1 = fmaf(bf_hi(v0.x), w0, A1);
        A2 = fmaf(bf_lo(v0.y), w0, A2);
        A3 = fmaf(bf_hi(v0.y), w0, A3);
        B0 = fmaf(bf_lo(v1.x), w1, B0);
        B1 = fmaf(bf_hi(v1.x), w1, B1);
        B2 = fmaf(bf_lo(v1.y), w1, B2);
        B3 = fmaf(bf_hi(v1.y), w1, B3);
        C0 = fmaf(bf_lo(v2.x), w2, C0);
        C1 = fmaf(bf_hi(v2.x), w2, C1);
        C2 = fmaf(bf_lo(v2.y), w2, C2);
        C3 = fmaf(bf_hi(v2.y), w2, C3);
        D0 = fmaf(bf_lo(v3.x), w3, D0);
        D1 = fmaf(bf_hi(v3.x), w3, D1);
        D2 = fmaf(bf_lo(v3.y), w3, D2);
        D3 = fmaf(bf_hi(v3.y), w3, D3);
    }

    // self-loop
    float d = dis[node];
    float w0 = d * d;
    uint2 hv = h[node * 32 + f];
    A0 = fmaf(bf_lo(hv.x), w0, A0);
    A1 = fmaf(bf_hi(hv.x), w0, A1);
    A2 = fmaf(bf_lo(hv.y), w0, A2);
    A3 = fmaf(bf_hi(hv.y), w0, A3);

    float a0 = (A0 + B0) + (C0 + D0);
    float a1 = (A1 + B1) + (C1 + D1);
    float a2 = (A2 + B2) + (C2 + D2);
    float a3 = (A3 + B3) + (C3 + D3);

    float4 b = ((const float4*)bias)[f];
    a0 = fmaxf(a0 + b.x, 0.f);
    a1 = fmaxf(a1 + b.y, 0.f);
    a2 = fmaxf(a2 + b.z, 0.f);
    a3 = fmaxf(a3 + b.w, 0.f);

    if (POOL == 0) {
        uint2 o;
        o.x = f2bf(a0) | (f2bf(a1) << 16);
        o.y = f2bf(a2) | (f2bf(a3) << 16);
        outbuf[node * 32 + f] = o;
    } else {
        int g = batch[node];
        float* o = sums + g * 128 + f * 4;
        atomicAdd(o + 0, a0);
        atomicAdd(o + 1, a1);
        atomicAdd(o + 2, a2);
        atomicAdd(o + 3, a3);
    }
}

// 512 blocks x 64 threads: pooled = sums/count; logits = pooled@Wf + bf; log_softmax
__global__ __launch_bounds__(64) void k_head(const float* __restrict__ sums,
                                             const float* __restrict__ counts,
                                             const float* __restrict__ Wf,
                                             const float* __restrict__ bf,
                                             float* __restrict__ out) {
    int g = blockIdx.x;
    int l = threadIdx.x;
    float inv = 1.0f / fmaxf(counts[g], 1.0f);
    float p0 = sums[g * 128 + l] * inv;
    float p1 = sums[g * 128 + 64 + l] * inv;
    float logit[10];
#pragma unroll
    for (int o = 0; o < 10; ++o) {
        float part = p0 * Wf[l * 10 + o] + p1 * Wf[(l + 64) * 10 + o];
#pragma unroll
        for (int s = 32; s > 0; s >>= 1) part += __shfl_xor(part, s);
        logit[o] = part + bf[o];
    }
    if (l == 0) {
        float m = logit[0];
#pragma unroll
        for (int o = 1; o < 10; ++o) m = fmaxf(m, logit[o]);
        float sum = 0.f;
#pragma unroll
        for (int o = 0; o < 10; ++o) sum += expf(logit[o] - m);
        float lse = m + logf(sum);
#pragma unroll
        for (int o = 0; o < 10; ++o) out[g * 10 + o] = logit[o] - lse;
    }
}

extern "C" void kernel_launch(void* const* d_in, const int* in_sizes, int n_in,
                              void* d_out, int out_size, void* d_ws, size_t ws_size,
                              hipStream_t stream) {
    const float* x     = (const float*)d_in[0];
    const int*   ei    = (const int*)d_in[1];
    const int*   batch = (const int*)d_in[2];
    const float* W0 = (const float*)d_in[3];
    const float* b0 = (const float*)d_in[4];
    const float* W1 = (const float*)d_in[5];
    const float* b1 = (const float*)d_in[6];
    const float* W2 = (const float*)d_in[7];
    const float* b2 = (const float*)d_in[8];
    const float* Wf = (const float*)d_in[9];
    const float* bf = (const float*)d_in[10];
    float* out = (float*)d_out;

    float* ws = (float*)d_ws;
    // float-offset layout
    float* sums    = ws;                      // 65536
    float* counts  = ws + 65536;              // 512
    int*   in_deg  = (int*)(ws + 66048);      // 50048
    int*   gcur    = (int*)(ws + 116096);     // 64
    float* dis     = ws + 116160;             // 50048
    int*   rowstart= (int*)(ws + 166208);     // 50048
    int*   cursor  = (int*)(ws + 216256);     // 50048
    uint2* cpk     = (uint2*)(ws + 266304);   // 800064 uint2 = 1600128 f (padded CSR)
    unsigned short* Wt = (unsigned short*)(ws + 1866432);   // 49152 ushort = 24576 f
    unsigned short* bx = (unsigned short*)(ws + 1891008);   // 3.2M f
    unsigned short* hA = (unsigned short*)(ws + 5091008);   // 3.2M f
    unsigned short* hB = (unsigned short*)(ws + 8291008);   // 3.2M f

    const int* src = ei;
    const int* dst = ei + NE;

    // --- CSR build + norms + pool counts + conversions ---
    k_zero<<<(116160 + 255) / 256, 256, 0, stream>>>(ws, 116160);
    k_hist<<<2344, 256, 0, stream>>>(dst, in_deg);
    k_counts<<<196, 256, 0, stream>>>(batch, counts);
    k_alloc<<<196, 256, 0, stream>>>(in_deg, gcur, rowstart, cursor, dis, cpk);
    k_fill<<<2344, 256, 0, stream>>>(src, dst, dis, cursor, cpk);
    k_cvt_x<<<6250, 256, 0, stream>>>((const float4*)x, (uint2*)bx, NN * 32);
    k_cvt_w<<<192, 256, 0, stream>>>(W0, W1, W2, Wt);

    const int GEMM_GRID = (NN + 63) / 64;

    // layer 0: bx -> hB (h@W0, bf16) -> hA (aggregate+bias+relu, bf16)
    k_gemm_mfma<<<GEMM_GRID, 256, 0, stream>>>(bx, Wt, hB, NN);
    k_gather<0><<<6250, 256, 0, stream>>>((const uint2*)hB, rowstart, cursor, cpk,
                                          dis, b0, (uint2*)hA, batch, sums);
    // layer 1
    k_gemm_mfma<<<GEMM_GRID, 256, 0, stream>>>(hA, Wt + 16384, hB, NN);
    k_gather<0><<<6250, 256, 0, stream>>>((const uint2*)hB, rowstart, cursor, cpk,
                                          dis, b1, (uint2*)hA, batch, sums);
    // layer 2: fuse bias+relu+mean-pool accumulate (f32 sums)
    k_gemm_mfma<<<GEMM_GRID, 256, 0, stream>>>(hA, Wt + 32768, hB, NN);
    k_gather<1><<<6250, 256, 0, stream>>>((const uint2*)hB, rowstart, cursor, cpk,
                                          dis, b2, nullptr, batch, sums);

    k_head<<<512, 64, 0, stream>>>(sums, counts, Wf, bf, out);
}